// Round 1
// baseline (4634.246 us; speedup 1.0000x reference)
//
#include <hip/hip_runtime.h>
#include <math.h>

// Problem constants (from reference): B=4, S=1024, D=512, H=8, HD=64, HID=2048
#define kB 4
#define kS 1024
#define kD 512
#define kH 8
#define kHD 64
#define kHID 2048
#define kNT (kB * kS)          // 4096 tokens
#define kBSD (kNT * kD)        // 2,097,152
#define kBSHID (kNT * kHID)    // 8,388,608
#define kDD (kD * kD)          // 262,144
#define kDH (kHID * kD)        // 1,048,576

// ---------------------------------------------------------------------------
// Weight build: wr = exp(lm)*cos(ph), wi = exp(lm)*sin(ph)
// ---------------------------------------------------------------------------
__global__ __launch_bounds__(256) void build_w_kernel(
    const float* __restrict__ lm, const float* __restrict__ ph,
    float* __restrict__ wr, float* __restrict__ wi, int n) {
  int i = blockIdx.x * 256 + threadIdx.x;
  if (i < n) {
    float m = expf(lm[i]);
    float s, c;
    sincosf(ph[i], &s, &c);
    wr[i] = m * c;
    wi[i] = m * s;
  }
}

// ---------------------------------------------------------------------------
// Complex LayerNorm: one block per token, D=512
// ---------------------------------------------------------------------------
__global__ __launch_bounds__(256) void cln_kernel(
    const float* __restrict__ xr, const float* __restrict__ xi,
    const float* __restrict__ g_r, const float* __restrict__ g_i,
    const float* __restrict__ b_r, const float* __restrict__ b_i,
    float* __restrict__ outr, float* __restrict__ outi) {
  __shared__ float red[256];
  int t = blockIdx.x;
  int tid = threadIdx.x;
  const float* xrt = xr + (size_t)t * kD;
  const float* xit = xi + (size_t)t * kD;

  float s1 = 0.f, s2 = 0.f;
  for (int d = tid; d < kD; d += 256) { s1 += xrt[d]; s2 += xit[d]; }

  red[tid] = s1; __syncthreads();
  for (int o = 128; o > 0; o >>= 1) { if (tid < o) red[tid] += red[tid + o]; __syncthreads(); }
  float mr = red[0] * (1.f / kD);
  __syncthreads();

  red[tid] = s2; __syncthreads();
  for (int o = 128; o > 0; o >>= 1) { if (tid < o) red[tid] += red[tid + o]; __syncthreads(); }
  float mi = red[0] * (1.f / kD);
  __syncthreads();

  float v = 0.f;
  for (int d = tid; d < kD; d += 256) {
    float cr = xrt[d] - mr, ci = xit[d] - mi;
    v += cr * cr + ci * ci;
  }
  red[tid] = v; __syncthreads();
  for (int o = 128; o > 0; o >>= 1) { if (tid < o) red[tid] += red[tid + o]; __syncthreads(); }
  float inv = rsqrtf(red[0] * (1.f / kD) + 1e-6f);

  for (int d = tid; d < kD; d += 256) {
    float nr = (xrt[d] - mr) * inv;
    float ni = (xit[d] - mi) * inv;
    outr[(size_t)t * kD + d] = nr * g_r[d] - ni * g_i[d] + b_r[d];
    outi[(size_t)t * kD + d] = nr * g_i[d] + ni * g_r[d] + b_i[d];
  }
}

// ---------------------------------------------------------------------------
// Generic complex GEMM: out[n][m] = x[n][:] (.) w[m][:] (complex), W is (M,K)
// optional bias (bm*cos(bp), bm*sin(bp)) and optional elementwise add (residual).
// 64x64 tile, K-tile 16, 256 threads, 4x4 outputs/thread.
// ---------------------------------------------------------------------------
__global__ __launch_bounds__(256) void cgemm_kernel(
    const float* __restrict__ xr, const float* __restrict__ xi,
    const float* __restrict__ wr, const float* __restrict__ wi,
    const float* __restrict__ bm, const float* __restrict__ bp,
    const float* __restrict__ adr, const float* __restrict__ adi,
    float* __restrict__ outr, float* __restrict__ outi,
    int N, int M, int K) {
  __shared__ float Xr[64][20], Xi[64][20], Wr[64][20], Wi[64][20];
  int tid = threadIdx.x;
  int tx = tid & 15, ty = tid >> 4;
  int m0 = blockIdx.x * 64, n0 = blockIdx.y * 64;
  int lr = tid >> 2;          // 0..63
  int lc = (tid & 3) * 4;     // 0,4,8,12

  float accr[4][4] = {}, acci[4][4] = {};

  for (int k0 = 0; k0 < K; k0 += 16) {
    *(float4*)&Xr[lr][lc] = *(const float4*)&xr[(size_t)(n0 + lr) * K + k0 + lc];
    *(float4*)&Xi[lr][lc] = *(const float4*)&xi[(size_t)(n0 + lr) * K + k0 + lc];
    *(float4*)&Wr[lr][lc] = *(const float4*)&wr[(size_t)(m0 + lr) * K + k0 + lc];
    *(float4*)&Wi[lr][lc] = *(const float4*)&wi[(size_t)(m0 + lr) * K + k0 + lc];
    __syncthreads();
#pragma unroll
    for (int kk = 0; kk < 16; ++kk) {
      float ar[4], ai[4], br_[4], bi_[4];
#pragma unroll
      for (int i = 0; i < 4; i++) { ar[i] = Xr[ty + 16 * i][kk]; ai[i] = Xi[ty + 16 * i][kk]; }
#pragma unroll
      for (int j = 0; j < 4; j++) { br_[j] = Wr[tx + 16 * j][kk]; bi_[j] = Wi[tx + 16 * j][kk]; }
#pragma unroll
      for (int i = 0; i < 4; i++)
#pragma unroll
        for (int j = 0; j < 4; j++) {
          accr[i][j] += ar[i] * br_[j] - ai[i] * bi_[j];
          acci[i][j] += ar[i] * bi_[j] + ai[i] * br_[j];
        }
    }
    __syncthreads();
  }

#pragma unroll
  for (int j = 0; j < 4; j++) {
    int gm = m0 + tx + 16 * j;
    float brr = 0.f, bii = 0.f;
    if (bm) {
      float s, c;
      sincosf(bp[gm], &s, &c);
      brr = bm[gm] * c;
      bii = bm[gm] * s;
    }
#pragma unroll
    for (int i = 0; i < 4; i++) {
      int gn = n0 + ty + 16 * i;
      size_t o = (size_t)gn * M + gm;
      float r = accr[i][j] + brr;
      float im = acci[i][j] + bii;
      if (adr) { r += adr[o]; im += adi[o]; }
      outr[o] = r;
      outi[o] = im;
    }
  }
}

// ---------------------------------------------------------------------------
// Fused FFN gate+up: computes gate & up complex GEMMs in one pass, applies
// s = sigmoid(|gate|), hid = (gate*s) * up (complex product).
// ---------------------------------------------------------------------------
__global__ __launch_bounds__(256) void ffn_gateup_kernel(
    const float* __restrict__ xr, const float* __restrict__ xi,
    const float* __restrict__ wgr, const float* __restrict__ wgi,
    const float* __restrict__ wur, const float* __restrict__ wui,
    float* __restrict__ hidr, float* __restrict__ hidi,
    int N, int M, int K) {
  __shared__ float Xr[64][20], Xi[64][20], Gr[64][20], Gi[64][20], Ur[64][20], Ui[64][20];
  int tid = threadIdx.x;
  int tx = tid & 15, ty = tid >> 4;
  int m0 = blockIdx.x * 64, n0 = blockIdx.y * 64;
  int lr = tid >> 2, lc = (tid & 3) * 4;

  float agr[4][4] = {}, agi[4][4] = {}, aur[4][4] = {}, aui[4][4] = {};

  for (int k0 = 0; k0 < K; k0 += 16) {
    *(float4*)&Xr[lr][lc] = *(const float4*)&xr[(size_t)(n0 + lr) * K + k0 + lc];
    *(float4*)&Xi[lr][lc] = *(const float4*)&xi[(size_t)(n0 + lr) * K + k0 + lc];
    *(float4*)&Gr[lr][lc] = *(const float4*)&wgr[(size_t)(m0 + lr) * K + k0 + lc];
    *(float4*)&Gi[lr][lc] = *(const float4*)&wgi[(size_t)(m0 + lr) * K + k0 + lc];
    *(float4*)&Ur[lr][lc] = *(const float4*)&wur[(size_t)(m0 + lr) * K + k0 + lc];
    *(float4*)&Ui[lr][lc] = *(const float4*)&wui[(size_t)(m0 + lr) * K + k0 + lc];
    __syncthreads();
#pragma unroll
    for (int kk = 0; kk < 16; ++kk) {
      float ar[4], ai[4];
#pragma unroll
      for (int i = 0; i < 4; i++) { ar[i] = Xr[ty + 16 * i][kk]; ai[i] = Xi[ty + 16 * i][kk]; }
#pragma unroll
      for (int j = 0; j < 4; j++) {
        float gw_r = Gr[tx + 16 * j][kk], gw_i = Gi[tx + 16 * j][kk];
        float uw_r = Ur[tx + 16 * j][kk], uw_i = Ui[tx + 16 * j][kk];
#pragma unroll
        for (int i = 0; i < 4; i++) {
          agr[i][j] += ar[i] * gw_r - ai[i] * gw_i;
          agi[i][j] += ar[i] * gw_i + ai[i] * gw_r;
          aur[i][j] += ar[i] * uw_r - ai[i] * uw_i;
          aui[i][j] += ar[i] * uw_i + ai[i] * uw_r;
        }
      }
    }
    __syncthreads();
  }

#pragma unroll
  for (int i = 0; i < 4; i++) {
    int gn = n0 + ty + 16 * i;
#pragma unroll
    for (int j = 0; j < 4; j++) {
      int gm = m0 + tx + 16 * j;
      float grv = agr[i][j], giv = agi[i][j], urv = aur[i][j], uiv = aui[i][j];
      float mag = sqrtf(grv * grv + giv * giv);
      float sg = 1.f / (1.f + __expf(-mag));
      float gar = grv * sg, gai = giv * sg;
      size_t o = (size_t)gn * M + gm;
      hidr[o] = gar * urv - gai * uiv;
      hidi[o] = gar * uiv + gai * urv;
    }
  }
}

// ---------------------------------------------------------------------------
// RoPE: in-place on qr,qi,kr,ki. Same real rotation on real & imag parts.
// One thread per (b,s,h,i) pair with i in [0,32): rotates (i, i+32).
// ---------------------------------------------------------------------------
__global__ __launch_bounds__(256) void rope_kernel(
    float* __restrict__ qr, float* __restrict__ qi,
    float* __restrict__ kr, float* __restrict__ ki) {
  int idx = blockIdx.x * 256 + threadIdx.x;  // 0 .. B*S*H*32-1
  int i = idx & 31;
  int h = (idx >> 5) & (kH - 1);
  int s = (idx >> 8) & (kS - 1);
  int b = idx >> 18;
  // inv_freq = 10000^(-i/32) = exp(-i*ln(10000)/32)
  float inv = expf(-(float)i * (9.210340371976184f / 32.0f));
  float f = (float)s * inv;
  float sn, cs;
  sincosf(f, &sn, &cs);
  size_t base = ((size_t)(b * kS + s)) * kD + h * kHD + i;

  float x0, x1;
  x0 = qr[base]; x1 = qr[base + 32];
  qr[base] = x0 * cs - x1 * sn; qr[base + 32] = x1 * cs + x0 * sn;
  x0 = qi[base]; x1 = qi[base + 32];
  qi[base] = x0 * cs - x1 * sn; qi[base + 32] = x1 * cs + x0 * sn;
  x0 = kr[base]; x1 = kr[base + 32];
  kr[base] = x0 * cs - x1 * sn; kr[base + 32] = x1 * cs + x0 * sn;
  x0 = ki[base]; x1 = ki[base + 32];
  ki[base] = x0 * cs - x1 * sn; ki[base + 32] = x1 * cs + x0 * sn;
}

// ---------------------------------------------------------------------------
// Flash-style causal Hermitian attention.
// One block per (b, h, q-tile of 32). 256 threads. K-tiles of 32.
// score = (qr.kr + qi.ki) * 1/sqrt(HD); online softmax; acc of vr & vi.
// LDS: 6*[32][68] + Sc[32][33] + 2*32 floats = 56.7 KB (< 64 KB/WG).
// ---------------------------------------------------------------------------
__global__ __launch_bounds__(256) void attn_kernel(
    const float* __restrict__ qr, const float* __restrict__ qi,
    const float* __restrict__ kr, const float* __restrict__ ki,
    const float* __restrict__ vr, const float* __restrict__ vi,
    float* __restrict__ outr, float* __restrict__ outi) {
  __shared__ float Qr[32][68], Qi[32][68];
  __shared__ float Kr[32][68], Ki[32][68], Vr[32][68], Vi[32][68];
  __shared__ float Sc[32][33];
  __shared__ float rowa[32], rowl[32];

  int t = threadIdx.x;
  int bid = blockIdx.x;
  int qt = bid & 31;          // q-tile (S/32 = 32)
  int h = (bid >> 5) & 7;
  int b = bid >> 8;
  int q0 = qt * 32;
  size_t hoff = (size_t)h * kHD;

  // ---- load Q tile (32 rows x 64 dims, both r & i) ----
  {
    int r = t >> 3, c0 = (t & 7) * 8;
    size_t g = ((size_t)(b * kS + q0 + r)) * kD + hoff + c0;
    *(float4*)&Qr[r][c0] = *(const float4*)&qr[g];
    *(float4*)&Qr[r][c0 + 4] = *(const float4*)&qr[g + 4];
    *(float4*)&Qi[r][c0] = *(const float4*)&qi[g];
    *(float4*)&Qi[r][c0 + 4] = *(const float4*)&qi[g + 4];
  }

  float accr[8] = {}, acci[8] = {};
  float m_i = -1e30f, l_i = 0.f;
  const float scale = 0.125f;  // 1/sqrt(64)

  int tx = t & 15, ty = t >> 4;    // score phase: 2x2 scores per thread
  int q_a = t & 31, dc = t >> 5;   // accum phase: (q, 8-dim chunk)
  int d0 = dc * 8;

  for (int kt = 0; kt <= qt; ++kt) {
    int k0 = kt * 32;
    __syncthreads();  // previous tile fully consumed (also guards Q load, iter 0)
    {
      int r = t >> 3, c0 = (t & 7) * 8;
      size_t g = ((size_t)(b * kS + k0 + r)) * kD + hoff + c0;
      *(float4*)&Kr[r][c0] = *(const float4*)&kr[g];
      *(float4*)&Kr[r][c0 + 4] = *(const float4*)&kr[g + 4];
      *(float4*)&Ki[r][c0] = *(const float4*)&ki[g];
      *(float4*)&Ki[r][c0 + 4] = *(const float4*)&ki[g + 4];
      *(float4*)&Vr[r][c0] = *(const float4*)&vr[g];
      *(float4*)&Vr[r][c0 + 4] = *(const float4*)&vr[g + 4];
      *(float4*)&Vi[r][c0] = *(const float4*)&vi[g];
      *(float4*)&Vi[r][c0 + 4] = *(const float4*)&vi[g + 4];
    }
    __syncthreads();

    // ---- scores: 2x2 per thread over 64 dims (float4 along d) ----
    {
      float sc[2][2] = {};
      const float4* q4r0 = (const float4*)&Qr[ty][0];
      const float4* q4r1 = (const float4*)&Qr[ty + 16][0];
      const float4* q4i0 = (const float4*)&Qi[ty][0];
      const float4* q4i1 = (const float4*)&Qi[ty + 16][0];
      const float4* k4r0 = (const float4*)&Kr[tx][0];
      const float4* k4r1 = (const float4*)&Kr[tx + 16][0];
      const float4* k4i0 = (const float4*)&Ki[tx][0];
      const float4* k4i1 = (const float4*)&Ki[tx + 16][0];
#pragma unroll
      for (int d4 = 0; d4 < 16; ++d4) {
        float4 a0 = q4r0[d4], a1 = q4r1[d4], c0_ = q4i0[d4], c1 = q4i1[d4];
        float4 b0 = k4r0[d4], b1 = k4r1[d4], e0 = k4i0[d4], e1 = k4i1[d4];
        sc[0][0] += a0.x * b0.x + a0.y * b0.y + a0.z * b0.z + a0.w * b0.w
                  + c0_.x * e0.x + c0_.y * e0.y + c0_.z * e0.z + c0_.w * e0.w;
        sc[0][1] += a0.x * b1.x + a0.y * b1.y + a0.z * b1.z + a0.w * b1.w
                  + c0_.x * e1.x + c0_.y * e1.y + c0_.z * e1.z + c0_.w * e1.w;
        sc[1][0] += a1.x * b0.x + a1.y * b0.y + a1.z * b0.z + a1.w * b0.w
                  + c1.x * e0.x + c1.y * e0.y + c1.z * e0.z + c1.w * e0.w;
        sc[1][1] += a1.x * b1.x + a1.y * b1.y + a1.z * b1.z + a1.w * b1.w
                  + c1.x * e1.x + c1.y * e1.y + c1.z * e1.z + c1.w * e1.w;
      }
      bool diag = (kt == qt);
#pragma unroll
      for (int i = 0; i < 2; i++)
#pragma unroll
        for (int j = 0; j < 2; j++) {
          int q = ty + 16 * i, k = tx + 16 * j;
          float sv = sc[i][j] * scale;
          if (diag && k > q) sv = -1e9f;
          Sc[q][k] = sv;
        }
    }
    __syncthreads();

    // ---- online softmax (one thread per q row) ----
    if (t < 32) {
      float mx = m_i;
#pragma unroll
      for (int k = 0; k < 32; k++) mx = fmaxf(mx, Sc[t][k]);
      float alpha = __expf(m_i - mx);
      float sum = 0.f;
#pragma unroll
      for (int k = 0; k < 32; k++) {
        float p = __expf(Sc[t][k] - mx);
        Sc[t][k] = p;
        sum += p;
      }
      l_i = l_i * alpha + sum;
      m_i = mx;
      rowa[t] = alpha;
    }
    __syncthreads();

    // ---- accumulate P @ V ----
    {
      float alpha = rowa[q_a];
#pragma unroll
      for (int j = 0; j < 8; j++) { accr[j] *= alpha; acci[j] *= alpha; }
      for (int k = 0; k < 32; k++) {
        float p = Sc[q_a][k];
        float4 v0 = *(const float4*)&Vr[k][d0];
        float4 v1 = *(const float4*)&Vr[k][d0 + 4];
        float4 w0 = *(const float4*)&Vi[k][d0];
        float4 w1 = *(const float4*)&Vi[k][d0 + 4];
        accr[0] += p * v0.x; accr[1] += p * v0.y; accr[2] += p * v0.z; accr[3] += p * v0.w;
        accr[4] += p * v1.x; accr[5] += p * v1.y; accr[6] += p * v1.z; accr[7] += p * v1.w;
        acci[0] += p * w0.x; acci[1] += p * w0.y; acci[2] += p * w0.z; acci[3] += p * w0.w;
        acci[4] += p * w1.x; acci[5] += p * w1.y; acci[6] += p * w1.z; acci[7] += p * w1.w;
      }
    }
  }

  __syncthreads();
  if (t < 32) rowl[t] = l_i;
  __syncthreads();
  {
    float inv = 1.f / rowl[q_a];
#pragma unroll
    for (int j = 0; j < 8; j++) {
      Qr[q_a][d0 + j] = accr[j] * inv;   // stage through LDS for coalesced store
      Qi[q_a][d0 + j] = acci[j] * inv;
    }
  }
  __syncthreads();
  {
    int r = t >> 3, c0 = (t & 7) * 8;
    size_t g = ((size_t)(b * kS + q0 + r)) * kD + hoff + c0;
    *(float4*)&outr[g] = *(const float4*)&Qr[r][c0];
    *(float4*)&outr[g + 4] = *(const float4*)&Qr[r][c0 + 4];
    *(float4*)&outi[g] = *(const float4*)&Qi[r][c0];
    *(float4*)&outi[g + 4] = *(const float4*)&Qi[r][c0 + 4];
  }
}

// ---------------------------------------------------------------------------
// Launcher
// ---------------------------------------------------------------------------
extern "C" void kernel_launch(void* const* d_in, const int* in_sizes, int n_in,
                              void* d_out, int out_size, void* d_ws, size_t ws_size,
                              hipStream_t stream) {
  const float* x_real = (const float*)d_in[0];
  const float* x_imag = (const float*)d_in[1];
  const float* ln1_gr = (const float*)d_in[2];
  const float* ln1_gi = (const float*)d_in[3];
  const float* ln1_br = (const float*)d_in[4];
  const float* ln1_bi = (const float*)d_in[5];
  const float* q_lm = (const float*)d_in[6];
  const float* q_ph = (const float*)d_in[7];
  const float* q_bm = (const float*)d_in[8];
  const float* q_bp = (const float*)d_in[9];
  const float* k_lm = (const float*)d_in[10];
  const float* k_ph = (const float*)d_in[11];
  const float* k_bm = (const float*)d_in[12];
  const float* k_bp = (const float*)d_in[13];
  const float* v_lm = (const float*)d_in[14];
  const float* v_ph = (const float*)d_in[15];
  const float* v_bm = (const float*)d_in[16];
  const float* v_bp = (const float*)d_in[17];
  const float* o_lm = (const float*)d_in[18];
  const float* o_ph = (const float*)d_in[19];
  const float* o_bm = (const float*)d_in[20];
  const float* o_bp = (const float*)d_in[21];
  const float* ln2_gr = (const float*)d_in[22];
  const float* ln2_gi = (const float*)d_in[23];
  const float* ln2_br = (const float*)d_in[24];
  const float* ln2_bi = (const float*)d_in[25];
  const float* gate_lm = (const float*)d_in[26];
  const float* gate_ph = (const float*)d_in[27];
  const float* up_lm = (const float*)d_in[28];
  const float* up_ph = (const float*)d_in[29];
  const float* down_lm = (const float*)d_in[30];
  const float* down_ph = (const float*)d_in[31];

  float* ws = (float*)d_ws;
  // Workspace layout (floats). Total 33,554,432 floats = 128 MiB.
  //  [0, 8.39M)          weights (persistent)
  //  region A (4.19M):   h (ln1 out) -> attn out -> h2 (ln2 out)
  //  region C (4.19M):   res (residual after o-proj)
  //  region B (16.78M):  q,k,v (6 x BSD) then reused as hid (2 x BSHID)
  float* wqr = ws + 0 * (size_t)kDD;
  float* wqi = ws + 1 * (size_t)kDD;
  float* wkr = ws + 2 * (size_t)kDD;
  float* wki = ws + 3 * (size_t)kDD;
  float* wvr = ws + 4 * (size_t)kDD;
  float* wvi = ws + 5 * (size_t)kDD;
  float* wor = ws + 6 * (size_t)kDD;
  float* woi = ws + 7 * (size_t)kDD;
  float* wgr = ws + 8 * (size_t)kDD + 0 * (size_t)kDH;
  float* wgi = ws + 8 * (size_t)kDD + 1 * (size_t)kDH;
  float* wur = ws + 8 * (size_t)kDD + 2 * (size_t)kDH;
  float* wui = ws + 8 * (size_t)kDD + 3 * (size_t)kDH;
  float* wdr = ws + 8 * (size_t)kDD + 4 * (size_t)kDH;
  float* wdi = ws + 8 * (size_t)kDD + 5 * (size_t)kDH;

  size_t off_A = 8 * (size_t)kDD + 6 * (size_t)kDH;  // 8,388,608
  float* Ar = ws + off_A;
  float* Ai = Ar + kBSD;
  size_t off_C = off_A + 2 * (size_t)kBSD;
  float* Cr = ws + off_C;
  float* Ci = Cr + kBSD;
  size_t off_B = off_C + 2 * (size_t)kBSD;
  float* qr = ws + off_B + 0 * (size_t)kBSD;
  float* qi = ws + off_B + 1 * (size_t)kBSD;
  float* kr = ws + off_B + 2 * (size_t)kBSD;
  float* ki = ws + off_B + 3 * (size_t)kBSD;
  float* vr = ws + off_B + 4 * (size_t)kBSD;
  float* vi = ws + off_B + 5 * (size_t)kBSD;
  float* hid_r = ws + off_B;            // reuses q..v space after attention
  float* hid_i = hid_r + (size_t)kBSHID;

  float* outr = (float*)d_out;
  float* outi = outr + kBSD;

  // 1) build weights
  build_w_kernel<<<kDD / 256, 256, 0, stream>>>(q_lm, q_ph, wqr, wqi, kDD);
  build_w_kernel<<<kDD / 256, 256, 0, stream>>>(k_lm, k_ph, wkr, wki, kDD);
  build_w_kernel<<<kDD / 256, 256, 0, stream>>>(v_lm, v_ph, wvr, wvi, kDD);
  build_w_kernel<<<kDD / 256, 256, 0, stream>>>(o_lm, o_ph, wor, woi, kDD);
  build_w_kernel<<<kDH / 256, 256, 0, stream>>>(gate_lm, gate_ph, wgr, wgi, kDH);
  build_w_kernel<<<kDH / 256, 256, 0, stream>>>(up_lm, up_ph, wur, wui, kDH);
  build_w_kernel<<<kDH / 256, 256, 0, stream>>>(down_lm, down_ph, wdr, wdi, kDH);

  // 2) LN1: x -> A (h)
  cln_kernel<<<kNT, 256, 0, stream>>>(x_real, x_imag, ln1_gr, ln1_gi, ln1_br, ln1_bi, Ar, Ai);

  // 3) QKV projections
  dim3 gD(kD / 64, kNT / 64);  // (8, 64)
  cgemm_kernel<<<gD, 256, 0, stream>>>(Ar, Ai, wqr, wqi, q_bm, q_bp, nullptr, nullptr, qr, qi, kNT, kD, kD);
  cgemm_kernel<<<gD, 256, 0, stream>>>(Ar, Ai, wkr, wki, k_bm, k_bp, nullptr, nullptr, kr, ki, kNT, kD, kD);
  cgemm_kernel<<<gD, 256, 0, stream>>>(Ar, Ai, wvr, wvi, v_bm, v_bp, nullptr, nullptr, vr, vi, kNT, kD, kD);

  // 4) RoPE on q, k
  rope_kernel<<<(kB * kS * kH * 32) / 256, 256, 0, stream>>>(qr, qi, kr, ki);

  // 5) attention -> A
  attn_kernel<<<kB * kH * (kS / 32), 256, 0, stream>>>(qr, qi, kr, ki, vr, vi, Ar, Ai);

  // 6) O projection + residual: res = x + clinear(attn) -> C
  cgemm_kernel<<<gD, 256, 0, stream>>>(Ar, Ai, wor, woi, o_bm, o_bp, x_real, x_imag, Cr, Ci, kNT, kD, kD);

  // 7) LN2: C -> A (h2)
  cln_kernel<<<kNT, 256, 0, stream>>>(Cr, Ci, ln2_gr, ln2_gi, ln2_br, ln2_bi, Ar, Ai);

  // 8) FFN gate+up fused -> hid (region B)
  dim3 gH(kHID / 64, kNT / 64);  // (32, 64)
  ffn_gateup_kernel<<<gH, 256, 0, stream>>>(Ar, Ai, wgr, wgi, wur, wui, hid_r, hid_i, kNT, kHID, kD);

  // 9) down projection + residual -> d_out
  cgemm_kernel<<<gD, 256, 0, stream>>>(hid_r, hid_i, wdr, wdi, nullptr, nullptr, Cr, Ci, outr, outi, kNT, kD, kHID);
}

// Round 2
// 899.692 us; speedup vs baseline: 5.1509x; 5.1509x over previous
//
#include <hip/hip_runtime.h>
#include <math.h>

// Problem constants: B=4, S=1024, D=512, H=8, HD=64, HID=2048
#define kB 4
#define kS 1024
#define kD 512
#define kH 8
#define kHD 64
#define kHID 2048
#define kNT (kB * kS)          // 4096 tokens
#define kBSD (kNT * kD)        // 2,097,152
#define kDD (kD * kD)          // 262,144
#define kDH (kHID * kD)        // 1,048,576

typedef __attribute__((ext_vector_type(8))) short bf16x8;
typedef __attribute__((ext_vector_type(4))) float f32x4;

#define AS1 __attribute__((address_space(1)))
#define AS3 __attribute__((address_space(3)))

__device__ __forceinline__ float bf2f(unsigned short u) {
  return __uint_as_float(((unsigned int)u) << 16);
}
__device__ __forceinline__ unsigned short f2bf(float f) {
  unsigned int u = __float_as_uint(f);
  u += 0x7fffu + ((u >> 16) & 1u);   // RNE
  return (unsigned short)(u >> 16);
}
__device__ __forceinline__ void unpack8(uint4 u, float* d) {
  d[0] = __uint_as_float(u.x << 16);
  d[1] = __uint_as_float(u.x & 0xffff0000u);
  d[2] = __uint_as_float(u.y << 16);
  d[3] = __uint_as_float(u.y & 0xffff0000u);
  d[4] = __uint_as_float(u.z << 16);
  d[5] = __uint_as_float(u.z & 0xffff0000u);
  d[6] = __uint_as_float(u.w << 16);
  d[7] = __uint_as_float(u.w & 0xffff0000u);
}

// ---------------------------------------------------------------------------
// Build concatenated bf16 weight block: for complex W (M,K) from lm/ph,
// writes a (2M x 2K) real block at dst (row stride 2K):
//   rows 0..M-1:   [ wr | -wi ]
//   rows M..2M-1:  [ wi |  wr ]
// ---------------------------------------------------------------------------
__global__ __launch_bounds__(256) void build_wcat_kernel(
    const float* __restrict__ lm, const float* __restrict__ ph,
    unsigned short* __restrict__ dst, int M, int K, int kshift) {
  int id = blockIdx.x * 256 + threadIdx.x;
  if (id >= M * K) return;
  int m = id >> kshift, k = id & (K - 1);
  float mm = expf(lm[id]);
  float s, c;
  sincosf(ph[id], &s, &c);
  float wr = mm * c, wi = mm * s;
  size_t ld = 2 * (size_t)K;
  dst[(size_t)m * ld + k] = f2bf(wr);
  dst[(size_t)m * ld + K + k] = f2bf(-wi);
  dst[(size_t)(M + m) * ld + k] = f2bf(wi);
  dst[(size_t)(M + m) * ld + K + k] = f2bf(wr);
}

// bias: dst[m] = bm*cos(bp), dst[M+m] = bm*sin(bp)
__global__ __launch_bounds__(256) void build_bias_kernel(
    const float* __restrict__ bm, const float* __restrict__ bp,
    float* __restrict__ dst, int M) {
  int m = blockIdx.x * 256 + threadIdx.x;
  if (m < M) {
    float s, c;
    sincosf(bp[m], &s, &c);
    dst[m] = bm[m] * c;
    dst[M + m] = bm[m] * s;
  }
}

// ---------------------------------------------------------------------------
// Complex LayerNorm: one block per token. Input fp32 (xr,xi with row stride),
// output bf16 (N,1024) cat layout [r | i].
// ---------------------------------------------------------------------------
__global__ __launch_bounds__(256) void cln_kernel(
    const float* __restrict__ xr, const float* __restrict__ xi, int stride,
    const float* __restrict__ g_r, const float* __restrict__ g_i,
    const float* __restrict__ b_r, const float* __restrict__ b_i,
    unsigned short* __restrict__ out) {
  __shared__ float red[256];
  int t = blockIdx.x;
  int tid = threadIdx.x;
  const float* xrt = xr + (size_t)t * stride;
  const float* xit = xi + (size_t)t * stride;

  float s1 = 0.f, s2 = 0.f;
  for (int d = tid; d < kD; d += 256) { s1 += xrt[d]; s2 += xit[d]; }
  red[tid] = s1; __syncthreads();
  for (int o = 128; o > 0; o >>= 1) { if (tid < o) red[tid] += red[tid + o]; __syncthreads(); }
  float mr = red[0] * (1.f / kD);
  __syncthreads();
  red[tid] = s2; __syncthreads();
  for (int o = 128; o > 0; o >>= 1) { if (tid < o) red[tid] += red[tid + o]; __syncthreads(); }
  float mi = red[0] * (1.f / kD);
  __syncthreads();
  float v = 0.f;
  for (int d = tid; d < kD; d += 256) {
    float cr = xrt[d] - mr, ci = xit[d] - mi;
    v += cr * cr + ci * ci;
  }
  red[tid] = v; __syncthreads();
  for (int o = 128; o > 0; o >>= 1) { if (tid < o) red[tid] += red[tid + o]; __syncthreads(); }
  float inv = rsqrtf(red[0] * (1.f / kD) + 1e-6f);

  unsigned short* ot = out + (size_t)t * 1024;
  for (int d = tid; d < kD; d += 256) {
    float nr = (xrt[d] - mr) * inv;
    float ni = (xit[d] - mi) * inv;
    ot[d] = f2bf(nr * g_r[d] - ni * g_i[d] + b_r[d]);
    ot[512 + d] = f2bf(nr * g_i[d] + ni * g_r[d] + b_i[d]);
  }
}

// ---------------------------------------------------------------------------
// bf16 MFMA GEMM: out[n][m] = sum_k X[n][k] * W[m][k]  (real GEMM, B^T form)
// X (N, K) bf16 row stride ldx; W (M, K) bf16 row-major.
// 128x128 tile, BK=32, 256 thr = 4 waves (2x2 of 64x64), 16x16x32 MFMA.
// global_load_lds width-16 staging (m97 structure).
// Epilogue modes:
//   0: out bf16 (N, ldo) at [row*ldo+col], += bias[col] if bias
//   1: O-proj: outf fp32 (N,1024) = acc + bias[col] + x residual (resr/resi fp32, stride 512)
//   2: down:   d_out fp32 split-halves = acc + resr[row*1024+col]
// ---------------------------------------------------------------------------
__global__ __launch_bounds__(256) void cgemm_mfma_kernel(
    const unsigned short* __restrict__ X, int ldx,
    const unsigned short* __restrict__ Wt, int K,
    const float* __restrict__ bias, int mode,
    const float* __restrict__ resr, const float* __restrict__ resi,
    unsigned short* __restrict__ outb, int ldo,
    float* __restrict__ outf) {
  __shared__ unsigned short Xs[128 * 32];
  __shared__ unsigned short Ws[128 * 32];

  const int tid = threadIdx.x;
  const int w = tid >> 6;
  const int lane = tid & 63;
  const int quad = lane >> 4;
  const int l15 = lane & 15;
  const int m0 = blockIdx.x * 128;
  const int n0 = blockIdx.y * 128;
  const int wm = (w & 1) * 64;
  const int wn = (w >> 1) * 64;

  // staging: 512 16B-chunks per tile; wave w stages chunks [w*128, w*128+128)
  const int idx0 = w * 128 + lane;
  const int idx1 = idx0 + 64;
  const int r0 = idx0 >> 2, c0 = (idx0 & 3) * 8;
  const int r1 = idx1 >> 2, c1 = (idx1 & 3) * 8;
  const unsigned short* gx0 = X + (size_t)(n0 + r0) * ldx + c0;
  const unsigned short* gx1 = X + (size_t)(n0 + r1) * ldx + c1;
  const unsigned short* gw0 = Wt + (size_t)(m0 + r0) * K + c0;
  const unsigned short* gw1 = Wt + (size_t)(m0 + r1) * K + c1;
  unsigned short* lx0 = &Xs[(w * 2 + 0) * 512];
  unsigned short* lx1 = &Xs[(w * 2 + 1) * 512];
  unsigned short* lw0 = &Ws[(w * 2 + 0) * 512];
  unsigned short* lw1 = &Ws[(w * 2 + 1) * 512];

  f32x4 acc[4][4];
#pragma unroll
  for (int i = 0; i < 4; i++)
#pragma unroll
    for (int j = 0; j < 4; j++) acc[i][j] = (f32x4){0.f, 0.f, 0.f, 0.f};

  for (int k0 = 0; k0 < K; k0 += 32) {
    __syncthreads();  // previous tile consumed
    __builtin_amdgcn_global_load_lds((const AS1 void*)(gx0 + k0), (AS3 void*)lx0, 16, 0, 0);
    __builtin_amdgcn_global_load_lds((const AS1 void*)(gx1 + k0), (AS3 void*)lx1, 16, 0, 0);
    __builtin_amdgcn_global_load_lds((const AS1 void*)(gw0 + k0), (AS3 void*)lw0, 16, 0, 0);
    __builtin_amdgcn_global_load_lds((const AS1 void*)(gw1 + k0), (AS3 void*)lw1, 16, 0, 0);
    __syncthreads();  // loads drained (barrier implies vmcnt(0))

    bf16x8 af[4], bf[4];
#pragma unroll
    for (int t = 0; t < 4; t++) {
      af[t] = *(const bf16x8*)&Xs[(wn + t * 16 + l15) * 32 + quad * 8];
      bf[t] = *(const bf16x8*)&Ws[(wm + t * 16 + l15) * 32 + quad * 8];
    }
#pragma unroll
    for (int i = 0; i < 4; i++)
#pragma unroll
      for (int j = 0; j < 4; j++)
        acc[i][j] = __builtin_amdgcn_mfma_f32_16x16x32_bf16(af[i], bf[j], acc[i][j], 0, 0, 0);
  }

  // epilogue: D mapping col=lane&15 (feature), row=(lane>>4)*4+reg (token)
#pragma unroll
  for (int j = 0; j < 4; ++j) {
    int col = m0 + wm + j * 16 + l15;
    float bv = bias ? bias[col] : 0.f;
#pragma unroll
    for (int i = 0; i < 4; ++i) {
      int row0 = n0 + wn + i * 16 + quad * 4;
#pragma unroll
      for (int r = 0; r < 4; ++r) {
        int row = row0 + r;
        float val = acc[i][j][r] + bv;
        if (mode == 0) {
          outb[(size_t)row * ldo + col] = f2bf(val);
        } else if (mode == 1) {
          float xres = (col < 512) ? resr[(size_t)row * 512 + col]
                                   : resi[(size_t)row * 512 + col - 512];
          outf[(size_t)row * 1024 + col] = val + xres;
        } else {
          float rv = resr[(size_t)row * 1024 + col] + val;
          size_t d = (col < 512) ? ((size_t)row * 512 + col)
                                 : ((size_t)kBSD + (size_t)row * 512 + (col - 512));
          outf[d] = rv;
        }
      }
    }
  }
}

// ---------------------------------------------------------------------------
// RoPE in place on bf16 qkv buffer (N, 3072): q cols [0,1024), k cols [1024,2048).
// One thread per (token, h, i<32); rotates pairs (i, i+32) of qr,qi,kr,ki.
// ---------------------------------------------------------------------------
__global__ __launch_bounds__(256) void rope_kernel(unsigned short* __restrict__ qkv) {
  int idx = blockIdx.x * 256 + threadIdx.x;  // 0 .. 4096*8*32-1
  int i = idx & 31;
  int h = (idx >> 5) & 7;
  int tok = idx >> 8;
  int s = tok & (kS - 1);
  float inv = expf(-(float)i * (9.210340371976184f / 32.0f));
  float f = (float)s * inv;
  float sn, cs;
  sincosf(f, &sn, &cs);
  size_t row = (size_t)tok * 3072;
  int hq = h * 64 + i;
#pragma unroll
  for (int comp = 0; comp < 4; comp++) {  // qr, qi, kr, ki
    size_t base = row + comp * 512 + hq;
    float x0 = bf2f(qkv[base]), x1 = bf2f(qkv[base + 32]);
    qkv[base] = f2bf(x0 * cs - x1 * sn);
    qkv[base + 32] = f2bf(x1 * cs + x0 * sn);
  }
}

// ---------------------------------------------------------------------------
// Flash-style causal Hermitian attention (fp32 VALU, bf16 in/out).
// qkv (N,3072): [qr|qi|kr|ki|vr|vi] per-head 64-wide blocks. out (N,1024) [ar|ai].
// One block per (b, h, q-tile of 32). 256 threads.
// ---------------------------------------------------------------------------
__global__ __launch_bounds__(256) void attn_kernel(
    const unsigned short* __restrict__ qkv, unsigned short* __restrict__ out) {
  __shared__ float Qr[32][68], Qi[32][68];
  __shared__ float Kr[32][68], Ki[32][68], Vr[32][68], Vi[32][68];
  __shared__ float Sc[32][33];
  __shared__ float rowa[32], rowl[32];

  int t = threadIdx.x;
  int bid = blockIdx.x;
  int qt = bid & 31;
  int h = (bid >> 5) & 7;
  int b = bid >> 8;
  int q0 = qt * 32;
  int hq = h * 64;

  {
    int r = t >> 3, c0 = (t & 7) * 8;
    size_t g = (size_t)(b * kS + q0 + r) * 3072 + hq + c0;
    unpack8(*(const uint4*)&qkv[g], &Qr[r][c0]);
    unpack8(*(const uint4*)&qkv[g + 512], &Qi[r][c0]);
  }

  float accr[8] = {}, acci[8] = {};
  float m_i = -1e30f, l_i = 0.f;
  const float scale = 0.125f;

  int tx = t & 15, ty = t >> 4;
  int q_a = t & 31, dc = t >> 5;
  int d0 = dc * 8;

  for (int kt = 0; kt <= qt; ++kt) {
    int k0 = kt * 32;
    __syncthreads();
    {
      int r = t >> 3, c0 = (t & 7) * 8;
      size_t g = (size_t)(b * kS + k0 + r) * 3072 + hq + c0;
      unpack8(*(const uint4*)&qkv[g + 1024], &Kr[r][c0]);
      unpack8(*(const uint4*)&qkv[g + 1536], &Ki[r][c0]);
      unpack8(*(const uint4*)&qkv[g + 2048], &Vr[r][c0]);
      unpack8(*(const uint4*)&qkv[g + 2560], &Vi[r][c0]);
    }
    __syncthreads();

    {
      float sc[2][2] = {};
      const float4* q4r0 = (const float4*)&Qr[ty][0];
      const float4* q4r1 = (const float4*)&Qr[ty + 16][0];
      const float4* q4i0 = (const float4*)&Qi[ty][0];
      const float4* q4i1 = (const float4*)&Qi[ty + 16][0];
      const float4* k4r0 = (const float4*)&Kr[tx][0];
      const float4* k4r1 = (const float4*)&Kr[tx + 16][0];
      const float4* k4i0 = (const float4*)&Ki[tx][0];
      const float4* k4i1 = (const float4*)&Ki[tx + 16][0];
#pragma unroll
      for (int d4 = 0; d4 < 16; ++d4) {
        float4 a0 = q4r0[d4], a1 = q4r1[d4], e0 = q4i0[d4], e1 = q4i1[d4];
        float4 b0 = k4r0[d4], b1 = k4r1[d4], f0 = k4i0[d4], f1 = k4i1[d4];
        sc[0][0] += a0.x * b0.x + a0.y * b0.y + a0.z * b0.z + a0.w * b0.w
                  + e0.x * f0.x + e0.y * f0.y + e0.z * f0.z + e0.w * f0.w;
        sc[0][1] += a0.x * b1.x + a0.y * b1.y + a0.z * b1.z + a0.w * b1.w
                  + e0.x * f1.x + e0.y * f1.y + e0.z * f1.z + e0.w * f1.w;
        sc[1][0] += a1.x * b0.x + a1.y * b0.y + a1.z * b0.z + a1.w * b0.w
                  + e1.x * f0.x + e1.y * f0.y + e1.z * f0.z + e1.w * f0.w;
        sc[1][1] += a1.x * b1.x + a1.y * b1.y + a1.z * b1.z + a1.w * b1.w
                  + e1.x * f1.x + e1.y * f1.y + e1.z * f1.z + e1.w * f1.w;
      }
      bool diag = (kt == qt);
#pragma unroll
      for (int i = 0; i < 2; i++)
#pragma unroll
        for (int j = 0; j < 2; j++) {
          int q = ty + 16 * i, k = tx + 16 * j;
          float sv = sc[i][j] * scale;
          if (diag && k > q) sv = -1e9f;
          Sc[q][k] = sv;
        }
    }
    __syncthreads();

    if (t < 32) {
      float mx = m_i;
#pragma unroll
      for (int k = 0; k < 32; k++) mx = fmaxf(mx, Sc[t][k]);
      float alpha = __expf(m_i - mx);
      float sum = 0.f;
#pragma unroll
      for (int k = 0; k < 32; k++) {
        float p = __expf(Sc[t][k] - mx);
        Sc[t][k] = p;
        sum += p;
      }
      l_i = l_i * alpha + sum;
      m_i = mx;
      rowa[t] = alpha;
    }
    __syncthreads();

    {
      float alpha = rowa[q_a];
#pragma unroll
      for (int j = 0; j < 8; j++) { accr[j] *= alpha; acci[j] *= alpha; }
      for (int k = 0; k < 32; k++) {
        float p = Sc[q_a][k];
        float4 v0 = *(const float4*)&Vr[k][d0];
        float4 v1 = *(const float4*)&Vr[k][d0 + 4];
        float4 w0 = *(const float4*)&Vi[k][d0];
        float4 w1 = *(const float4*)&Vi[k][d0 + 4];
        accr[0] += p * v0.x; accr[1] += p * v0.y; accr[2] += p * v0.z; accr[3] += p * v0.w;
        accr[4] += p * v1.x; accr[5] += p * v1.y; accr[6] += p * v1.z; accr[7] += p * v1.w;
        acci[0] += p * w0.x; acci[1] += p * w0.y; acci[2] += p * w0.z; acci[3] += p * w0.w;
        acci[4] += p * w1.x; acci[5] += p * w1.y; acci[6] += p * w1.z; acci[7] += p * w1.w;
      }
    }
  }

  __syncthreads();
  if (t < 32) rowl[t] = l_i;
  __syncthreads();
  {
    float inv = 1.f / rowl[q_a];
#pragma unroll
    for (int j = 0; j < 8; j++) {
      Qr[q_a][d0 + j] = accr[j] * inv;
      Qi[q_a][d0 + j] = acci[j] * inv;
    }
  }
  __syncthreads();
  {
    int r = t >> 3, c0 = (t & 7) * 8;
    size_t g = (size_t)(b * kS + q0 + r) * 1024 + hq + c0;
    unsigned int pr[4], pi[4];
#pragma unroll
    for (int e = 0; e < 4; e++) {
      pr[e] = (unsigned)f2bf(Qr[r][c0 + 2 * e]) | ((unsigned)f2bf(Qr[r][c0 + 2 * e + 1]) << 16);
      pi[e] = (unsigned)f2bf(Qi[r][c0 + 2 * e]) | ((unsigned)f2bf(Qi[r][c0 + 2 * e + 1]) << 16);
    }
    *(uint4*)&out[g] = make_uint4(pr[0], pr[1], pr[2], pr[3]);
    *(uint4*)&out[g + 512] = make_uint4(pi[0], pi[1], pi[2], pi[3]);
  }
}

// ---------------------------------------------------------------------------
// FFN gating, in place on gu (N, 8192) bf16 [gr|gi|ur|ui]:
// hid = (g * sigmoid(|g|)) * u written to cols [0,2048) and [2048,4096).
// ---------------------------------------------------------------------------
__global__ __launch_bounds__(256) void gate_kernel(unsigned short* __restrict__ gu) {
  int id = blockIdx.x * 256 + threadIdx.x;  // 0 .. 4096*2048-1
  int n = id >> 11, m = id & 2047;
  size_t row = (size_t)n * 8192;
  float gr = bf2f(gu[row + m]);
  float gi = bf2f(gu[row + 2048 + m]);
  float ur = bf2f(gu[row + 4096 + m]);
  float ui = bf2f(gu[row + 6144 + m]);
  float mag = sqrtf(gr * gr + gi * gi);
  float s = 1.f / (1.f + __expf(-mag));
  float gar = gr * s, gai = gi * s;
  gu[row + m] = f2bf(gar * ur - gai * ui);
  gu[row + 2048 + m] = f2bf(gar * ui + gai * ur);
}

// ---------------------------------------------------------------------------
// Launcher
// ---------------------------------------------------------------------------
extern "C" void kernel_launch(void* const* d_in, const int* in_sizes, int n_in,
                              void* d_out, int out_size, void* d_ws, size_t ws_size,
                              hipStream_t stream) {
  const float* x_real = (const float*)d_in[0];
  const float* x_imag = (const float*)d_in[1];
  const float* ln1_gr = (const float*)d_in[2];
  const float* ln1_gi = (const float*)d_in[3];
  const float* ln1_br = (const float*)d_in[4];
  const float* ln1_bi = (const float*)d_in[5];
  const float* q_lm = (const float*)d_in[6];
  const float* q_ph = (const float*)d_in[7];
  const float* q_bm = (const float*)d_in[8];
  const float* q_bp = (const float*)d_in[9];
  const float* k_lm = (const float*)d_in[10];
  const float* k_ph = (const float*)d_in[11];
  const float* k_bm = (const float*)d_in[12];
  const float* k_bp = (const float*)d_in[13];
  const float* v_lm = (const float*)d_in[14];
  const float* v_ph = (const float*)d_in[15];
  const float* v_bm = (const float*)d_in[16];
  const float* v_bp = (const float*)d_in[17];
  const float* o_lm = (const float*)d_in[18];
  const float* o_ph = (const float*)d_in[19];
  const float* o_bm = (const float*)d_in[20];
  const float* o_bp = (const float*)d_in[21];
  const float* ln2_gr = (const float*)d_in[22];
  const float* ln2_gi = (const float*)d_in[23];
  const float* ln2_br = (const float*)d_in[24];
  const float* ln2_bi = (const float*)d_in[25];
  const float* gate_lm = (const float*)d_in[26];
  const float* gate_ph = (const float*)d_in[27];
  const float* up_lm = (const float*)d_in[28];
  const float* up_ph = (const float*)d_in[29];
  const float* down_lm = (const float*)d_in[30];
  const float* down_ph = (const float*)d_in[31];

  // ---- workspace layout (bytes), total 125,845,504 <= 128 MiB ----
  char* wsb = (char*)d_ws;
  unsigned short* Wqkv = (unsigned short*)(wsb + 0);           // 3072x1024 bf16 = 6,291,456
  unsigned short* Wo   = (unsigned short*)(wsb + 6291456);     // 1024x1024 bf16 = 2,097,152
  unsigned short* Wgu  = (unsigned short*)(wsb + 8388608);     // 8192x1024 bf16 = 16,777,216
  unsigned short* Wd   = (unsigned short*)(wsb + 25165824);    // 1024x4096 bf16 = 8,388,608
  float* qkvBias = (float*)(wsb + 33554432);                   // 3072 fp32
  float* oBias   = (float*)(wsb + 33566720);                   // 1024 fp32
  float* res     = (float*)(wsb + 33570816);                   // 4096x1024 fp32 = 16,777,216
  unsigned short* H = (unsigned short*)(wsb + 50348032);       // 4096x1024 bf16 (h1/h2)
  char* big = wsb + 58736640;                                  // 64 MiB region
  unsigned short* qkv     = (unsigned short*)big;              // 4096x3072 bf16 = 25,165,824
  unsigned short* attnout = (unsigned short*)(big + 25165824); // 4096x1024 bf16 = 8,388,608
  unsigned short* gu      = (unsigned short*)big;              // 4096x8192 bf16 = 67,108,864 (aliases qkv/attnout, dead by then)

  float* outf = (float*)d_out;  // (2, 4096, 512)

  // 1) build cat weights (bf16) + biases
  build_wcat_kernel<<<kDD / 256, 256, 0, stream>>>(q_lm, q_ph, Wqkv, 512, 512, 9);
  build_wcat_kernel<<<kDD / 256, 256, 0, stream>>>(k_lm, k_ph, Wqkv + (size_t)1024 * 1024, 512, 512, 9);
  build_wcat_kernel<<<kDD / 256, 256, 0, stream>>>(v_lm, v_ph, Wqkv + (size_t)2048 * 1024, 512, 512, 9);
  build_wcat_kernel<<<kDD / 256, 256, 0, stream>>>(o_lm, o_ph, Wo, 512, 512, 9);
  build_wcat_kernel<<<kDH / 256, 256, 0, stream>>>(gate_lm, gate_ph, Wgu, 2048, 512, 9);
  build_wcat_kernel<<<kDH / 256, 256, 0, stream>>>(up_lm, up_ph, Wgu + (size_t)4096 * 1024, 2048, 512, 9);
  build_wcat_kernel<<<kDH / 256, 256, 0, stream>>>(down_lm, down_ph, Wd, 512, 2048, 11);
  build_bias_kernel<<<2, 256, 0, stream>>>(q_bm, q_bp, qkvBias, 512);
  build_bias_kernel<<<2, 256, 0, stream>>>(k_bm, k_bp, qkvBias + 1024, 512);
  build_bias_kernel<<<2, 256, 0, stream>>>(v_bm, v_bp, qkvBias + 2048, 512);
  build_bias_kernel<<<2, 256, 0, stream>>>(o_bm, o_bp, oBias, 512);

  // 2) LN1: x -> H (bf16 cat)
  cln_kernel<<<kNT, 256, 0, stream>>>(x_real, x_imag, 512, ln1_gr, ln1_gi, ln1_br, ln1_bi, H);

  // 3) QKV fused GEMM: (4096,1024) x (3072,1024)^T -> qkv bf16
  {
    dim3 g(3072 / 128, kNT / 128);
    cgemm_mfma_kernel<<<g, 256, 0, stream>>>(H, 1024, Wqkv, 1024, qkvBias, 0,
                                             nullptr, nullptr, qkv, 3072, nullptr);
  }

  // 4) RoPE in place on q,k
  rope_kernel<<<(kNT * kH * 32) / 256, 256, 0, stream>>>(qkv);

  // 5) attention -> attnout bf16
  attn_kernel<<<kB * kH * (kS / 32), 256, 0, stream>>>(qkv, attnout);

  // 6) O-proj + x residual -> res fp32
  {
    dim3 g(1024 / 128, kNT / 128);
    cgemm_mfma_kernel<<<g, 256, 0, stream>>>(attnout, 1024, Wo, 1024, oBias, 1,
                                             x_real, x_imag, nullptr, 0, res);
  }

  // 7) LN2: res -> H (bf16 cat)
  cln_kernel<<<kNT, 256, 0, stream>>>(res, res + 512, 1024, ln2_gr, ln2_gi, ln2_br, ln2_bi, H);

  // 8) gate+up fused GEMM: (4096,1024) x (8192,1024)^T -> gu bf16
  {
    dim3 g(8192 / 128, kNT / 128);
    cgemm_mfma_kernel<<<g, 256, 0, stream>>>(H, 1024, Wgu, 1024, nullptr, 0,
                                             nullptr, nullptr, gu, 8192, nullptr);
  }

  // 9) gating in place: hid = (g*sigmoid(|g|))*u -> gu cols [0,4096)
  gate_kernel<<<(kNT * kHID) / 256, 256, 0, stream>>>(gu);

  // 10) down GEMM + res residual -> d_out fp32
  {
    dim3 g(1024 / 128, kNT / 128);
    cgemm_mfma_kernel<<<g, 256, 0, stream>>>(gu, 8192, Wd, 4096, nullptr, 2,
                                             res, nullptr, nullptr, 0, outf);
  }
}

// Round 3
// 586.340 us; speedup vs baseline: 7.9037x; 1.5344x over previous
//
#include <hip/hip_runtime.h>
#include <math.h>

// Problem constants: B=4, S=1024, D=512, H=8, HD=64, HID=2048
#define kB 4
#define kS 1024
#define kD 512
#define kH 8
#define kHD 64
#define kHID 2048
#define kNT (kB * kS)          // 4096 tokens
#define kBSD (kNT * kD)        // 2,097,152
#define kDD (kD * kD)          // 262,144
#define kDH (kHID * kD)        // 1,048,576

typedef __attribute__((ext_vector_type(8))) short bf16x8;
typedef __attribute__((ext_vector_type(4))) float f32x4;

#define AS1 __attribute__((address_space(1)))
#define AS3 __attribute__((address_space(3)))

__device__ __forceinline__ float bf2f(unsigned short u) {
  return __uint_as_float(((unsigned int)u) << 16);
}
__device__ __forceinline__ unsigned short f2bf(float f) {
  unsigned int u = __float_as_uint(f);
  u += 0x7fffu + ((u >> 16) & 1u);   // RNE
  return (unsigned short)(u >> 16);
}

// ---------------------------------------------------------------------------
// Standard cat-weight build (O, gate, up, down): complex W (M,K) ->
// (2M x 2K) real block, rows [wr|-wi] then [wi|wr].
// ---------------------------------------------------------------------------
__global__ __launch_bounds__(256) void build_wcat_kernel(
    const float* __restrict__ lm, const float* __restrict__ ph,
    unsigned short* __restrict__ dst, int M, int K, int kshift) {
  int id = blockIdx.x * 256 + threadIdx.x;
  if (id >= M * K) return;
  int m = id >> kshift, k = id & (K - 1);
  float mm = expf(lm[id]);
  float s, c;
  sincosf(ph[id], &s, &c);
  float wr = mm * c, wi = mm * s;
  size_t ld = 2 * (size_t)K;
  dst[(size_t)m * ld + k] = f2bf(wr);
  dst[(size_t)m * ld + K + k] = f2bf(-wi);
  dst[(size_t)(M + m) * ld + k] = f2bf(wi);
  dst[(size_t)(M + m) * ld + K + k] = f2bf(wr);
}

// ---------------------------------------------------------------------------
// Head-permuted QKV weight build: output col = blk*1024 + h*128 + ri*64 + d
// for complex feature m = h*64+d of matrix blk (0=q,1=k,2=v). ld = 1024.
// ---------------------------------------------------------------------------
__global__ __launch_bounds__(256) void build_wcat_perm_kernel(
    const float* __restrict__ lm, const float* __restrict__ ph,
    unsigned short* __restrict__ dst, int blk) {
  int id = blockIdx.x * 256 + threadIdx.x;  // m*512 + k
  if (id >= 512 * 512) return;
  int m = id >> 9, k = id & 511;
  float mm = expf(lm[id]);
  float s, c;
  sincosf(ph[id], &s, &c);
  float wr = mm * c, wi = mm * s;
  int h = m >> 6, d = m & 63;
  size_t rowR = (size_t)blk * 1024 + h * 128 + d;
  size_t rowI = rowR + 64;
  dst[rowR * 1024 + k] = f2bf(wr);
  dst[rowR * 1024 + 512 + k] = f2bf(-wi);
  dst[rowI * 1024 + k] = f2bf(wi);
  dst[rowI * 1024 + 512 + k] = f2bf(wr);
}

// standard bias: dst[m] = bm*cos(bp), dst[M+m] = bm*sin(bp)
__global__ __launch_bounds__(256) void build_bias_kernel(
    const float* __restrict__ bm, const float* __restrict__ bp,
    float* __restrict__ dst, int M) {
  int m = blockIdx.x * 256 + threadIdx.x;
  if (m < M) {
    float s, c;
    sincosf(bp[m], &s, &c);
    dst[m] = bm[m] * c;
    dst[M + m] = bm[m] * s;
  }
}

// head-permuted bias for QKV
__global__ __launch_bounds__(256) void build_bias_perm_kernel(
    const float* __restrict__ bm, const float* __restrict__ bp,
    float* __restrict__ dst, int blk) {
  int m = blockIdx.x * 256 + threadIdx.x;
  if (m < 512) {
    float s, c;
    sincosf(bp[m], &s, &c);
    int h = m >> 6, d = m & 63;
    dst[blk * 1024 + h * 128 + d] = bm[m] * c;
    dst[blk * 1024 + h * 128 + 64 + d] = bm[m] * s;
  }
}

// ---------------------------------------------------------------------------
// Complex LayerNorm: one block per token. fp32 in -> bf16 (N,1024) [r|i] out.
// ---------------------------------------------------------------------------
__global__ __launch_bounds__(256) void cln_kernel(
    const float* __restrict__ xr, const float* __restrict__ xi, int stride,
    const float* __restrict__ g_r, const float* __restrict__ g_i,
    const float* __restrict__ b_r, const float* __restrict__ b_i,
    unsigned short* __restrict__ out) {
  __shared__ float red[256];
  int t = blockIdx.x;
  int tid = threadIdx.x;
  const float* xrt = xr + (size_t)t * stride;
  const float* xit = xi + (size_t)t * stride;

  float s1 = 0.f, s2 = 0.f;
  for (int d = tid; d < kD; d += 256) { s1 += xrt[d]; s2 += xit[d]; }
  red[tid] = s1; __syncthreads();
  for (int o = 128; o > 0; o >>= 1) { if (tid < o) red[tid] += red[tid + o]; __syncthreads(); }
  float mr = red[0] * (1.f / kD);
  __syncthreads();
  red[tid] = s2; __syncthreads();
  for (int o = 128; o > 0; o >>= 1) { if (tid < o) red[tid] += red[tid + o]; __syncthreads(); }
  float mi = red[0] * (1.f / kD);
  __syncthreads();
  float v = 0.f;
  for (int d = tid; d < kD; d += 256) {
    float cr = xrt[d] - mr, ci = xit[d] - mi;
    v += cr * cr + ci * ci;
  }
  red[tid] = v; __syncthreads();
  for (int o = 128; o > 0; o >>= 1) { if (tid < o) red[tid] += red[tid + o]; __syncthreads(); }
  float inv = rsqrtf(red[0] * (1.f / kD) + 1e-6f);

  unsigned short* ot = out + (size_t)t * 1024;
  for (int d = tid; d < kD; d += 256) {
    float nr = (xrt[d] - mr) * inv;
    float ni = (xit[d] - mi) * inv;
    ot[d] = f2bf(nr * g_r[d] - ni * g_i[d] + b_r[d]);
    ot[512 + d] = f2bf(nr * g_i[d] + ni * g_r[d] + b_i[d]);
  }
}

// ---------------------------------------------------------------------------
// bf16 MFMA GEMM (m97 structure): out[n][m] = sum_k X[n][k]*W[m][k].
// 128x128 tile, BK=32, 4 waves, 16x16x32 MFMA, global_load_lds staging.
// Epilogue modes:
//   0: out bf16 (N,ldo), += bias[col]
//   1: O-proj: outf fp32 (N,1024) = acc + bias + x residual (resr/resi, stride 512)
//   2: down:   d_out fp32 split halves = acc + resr[row*1024+col]
//   3: QKV:    cols<2048 -> outb (ldo=3072); cols>=2048 -> vtb transposed
//              vt[b][h][dcat][s], packed 4-row 8B stores
// ---------------------------------------------------------------------------
__global__ __launch_bounds__(256) void cgemm_mfma_kernel(
    const unsigned short* __restrict__ X, int ldx,
    const unsigned short* __restrict__ Wt, int K,
    const float* __restrict__ bias, int mode,
    const float* __restrict__ resr, const float* __restrict__ resi,
    unsigned short* __restrict__ outb, int ldo,
    float* __restrict__ outf, unsigned short* __restrict__ vtb) {
  __shared__ unsigned short Xs[128 * 32];
  __shared__ unsigned short Ws[128 * 32];

  const int tid = threadIdx.x;
  const int w = tid >> 6;
  const int lane = tid & 63;
  const int quad = lane >> 4;
  const int l15 = lane & 15;
  const int m0 = blockIdx.x * 128;
  const int n0 = blockIdx.y * 128;
  const int wm = (w & 1) * 64;
  const int wn = (w >> 1) * 64;

  const int idx0 = w * 128 + lane;
  const int idx1 = idx0 + 64;
  const int r0 = idx0 >> 2, c0 = (idx0 & 3) * 8;
  const int r1 = idx1 >> 2, c1 = (idx1 & 3) * 8;
  const unsigned short* gx0 = X + (size_t)(n0 + r0) * ldx + c0;
  const unsigned short* gx1 = X + (size_t)(n0 + r1) * ldx + c1;
  const unsigned short* gw0 = Wt + (size_t)(m0 + r0) * K + c0;
  const unsigned short* gw1 = Wt + (size_t)(m0 + r1) * K + c1;
  unsigned short* lx0 = &Xs[(w * 2 + 0) * 512];
  unsigned short* lx1 = &Xs[(w * 2 + 1) * 512];
  unsigned short* lw0 = &Ws[(w * 2 + 0) * 512];
  unsigned short* lw1 = &Ws[(w * 2 + 1) * 512];

  f32x4 acc[4][4];
#pragma unroll
  for (int i = 0; i < 4; i++)
#pragma unroll
    for (int j = 0; j < 4; j++) acc[i][j] = (f32x4){0.f, 0.f, 0.f, 0.f};

  for (int k0 = 0; k0 < K; k0 += 32) {
    __syncthreads();
    __builtin_amdgcn_global_load_lds((const AS1 void*)(gx0 + k0), (AS3 void*)lx0, 16, 0, 0);
    __builtin_amdgcn_global_load_lds((const AS1 void*)(gx1 + k0), (AS3 void*)lx1, 16, 0, 0);
    __builtin_amdgcn_global_load_lds((const AS1 void*)(gw0 + k0), (AS3 void*)lw0, 16, 0, 0);
    __builtin_amdgcn_global_load_lds((const AS1 void*)(gw1 + k0), (AS3 void*)lw1, 16, 0, 0);
    __syncthreads();

    bf16x8 af[4], bf[4];
#pragma unroll
    for (int t = 0; t < 4; t++) {
      af[t] = *(const bf16x8*)&Xs[(wn + t * 16 + l15) * 32 + quad * 8];
      bf[t] = *(const bf16x8*)&Ws[(wm + t * 16 + l15) * 32 + quad * 8];
    }
#pragma unroll
    for (int i = 0; i < 4; i++)
#pragma unroll
      for (int j = 0; j < 4; j++)
        acc[i][j] = __builtin_amdgcn_mfma_f32_16x16x32_bf16(af[i], bf[j], acc[i][j], 0, 0, 0);
  }

  // epilogue: D mapping col=lane&15 (W-row/feature), row=(lane>>4)*4+reg (token)
#pragma unroll
  for (int j = 0; j < 4; ++j) {
    int col = m0 + wm + j * 16 + l15;
    float bv = bias ? bias[col] : 0.f;
#pragma unroll
    for (int i = 0; i < 4; ++i) {
      int row0 = n0 + wn + i * 16 + quad * 4;
      if (mode == 3 && col >= 2048) {
        // V transposed: vt[b][h][dcat][s], pack 4 consecutive tokens
        int hh = (col - 2048) >> 7, dcat = (col - 2048) & 127;
        int bb = row0 >> 10, s0 = row0 & 1023;
        ushort4 pk;
        pk.x = f2bf(acc[i][j][0] + bv);
        pk.y = f2bf(acc[i][j][1] + bv);
        pk.z = f2bf(acc[i][j][2] + bv);
        pk.w = f2bf(acc[i][j][3] + bv);
        *(ushort4*)&vtb[(size_t)((bb * 8 + hh) * 128 + dcat) * 1024 + s0] = pk;
      } else {
#pragma unroll
        for (int r = 0; r < 4; ++r) {
          int row = row0 + r;
          float val = acc[i][j][r] + bv;
          if (mode == 0 || mode == 3) {
            outb[(size_t)row * ldo + col] = f2bf(val);
          } else if (mode == 1) {
            float xres = (col < 512) ? resr[(size_t)row * 512 + col]
                                     : resi[(size_t)row * 512 + col - 512];
            outf[(size_t)row * 1024 + col] = val + xres;
          } else {
            float rv = resr[(size_t)row * 1024 + col] + val;
            size_t d = (col < 512) ? ((size_t)row * 512 + col)
                                   : ((size_t)kBSD + (size_t)row * 512 + (col - 512));
            outf[d] = rv;
          }
        }
      }
    }
  }
}

// ---------------------------------------------------------------------------
// RoPE in place on qkv (N,3072), head-permuted layout:
// q at col h*128+ri*64+d, k at 1024+h*128+ri*64+d. Pairs (i, i+32), i<32.
// ---------------------------------------------------------------------------
__global__ __launch_bounds__(256) void rope_kernel(unsigned short* __restrict__ qkv) {
  int idx = blockIdx.x * 256 + threadIdx.x;  // 0 .. 4096*8*32-1
  int i = idx & 31;
  int h = (idx >> 5) & 7;
  int tok = idx >> 8;
  int s = tok & (kS - 1);
  float inv = expf(-(float)i * (9.210340371976184f / 32.0f));
  float f = (float)s * inv;
  float sn, cs;
  sincosf(f, &sn, &cs);
  size_t base0 = (size_t)tok * 3072 + h * 128 + i;
  const int offs[4] = {0, 64, 1024, 1088};  // qr, qi, kr, ki
#pragma unroll
  for (int comp = 0; comp < 4; comp++) {
    size_t base = base0 + offs[comp];
    float x0 = bf2f(qkv[base]), x1 = bf2f(qkv[base + 32]);
    qkv[base] = f2bf(x0 * cs - x1 * sn);
    qkv[base + 32] = f2bf(x1 * cs + x0 * sn);
  }
}

// ---------------------------------------------------------------------------
// MFMA flash attention (causal, Hermitian). Block = (b,h,64-query tile),
// 4 waves x 16 q-rows. K-tile = 32 keys. Scores: K=128 cat (qr|qi).(kr|ki).
// Online softmax in registers (C-layout row reduce via shfl_xor over 16 lanes).
// P through per-wave LDS -> A-frag; PV against LDS-staged V^T tile.
// LDS: Ks 32x136 + Vs 128x40 + Ps 4x16x40 = 24,064 B.
// ---------------------------------------------------------------------------
__global__ __launch_bounds__(256) void attn_mfma_kernel(
    const unsigned short* __restrict__ qkv,   // (4096, 3072)
    const unsigned short* __restrict__ vt,    // (4,8,128,1024)
    unsigned short* __restrict__ out) {       // (4096, 1024) [ar|ai]
  __shared__ unsigned short Ks[32 * 136];
  __shared__ unsigned short Vs[128 * 40];
  __shared__ unsigned short Ps[4 * 16 * 40];

  const int tid = threadIdx.x;
  const int w = tid >> 6;
  const int lane = tid & 63;
  const int quad = lane >> 4;
  const int l15 = lane & 15;

  int bid = blockIdx.x;
  int qt = bid & 15;
  if ((bid >> 4) & 1) qt = 15 - qt;   // alternate heavy/light for balance
  const int h = (bid >> 4) & 7;
  const int b = bid >> 7;
  const int q0 = qt * 64;
  const int wrow0 = q0 + w * 16;      // wave's first query position

  // Q A-frags (k-steps over 128 cat dims), resident in registers
  bf16x8 qa[4];
  {
    size_t base = (size_t)(b * kS + wrow0 + l15) * 3072 + h * 128;
#pragma unroll
    for (int ks = 0; ks < 4; ks++)
      qa[ks] = *(const bf16x8*)&qkv[base + ks * 32 + quad * 8];
  }

  f32x4 oacc[8];
#pragma unroll
  for (int dt = 0; dt < 8; dt++) oacc[dt] = (f32x4){0.f, 0.f, 0.f, 0.f};
  float m_r[4] = {-1e30f, -1e30f, -1e30f, -1e30f};
  float l_r[4] = {0.f, 0.f, 0.f, 0.f};

  const int ktmax_blk = (q0 + 63) >> 5;
  const int ktmax_wav = (wrow0 + 15) >> 5;
  const float cexp = 0.1803368801f;  // (1/sqrt(64)) * log2(e)

  const unsigned short* gkbase = qkv + 1024 + h * 128;
  const unsigned short* gvbase = vt + (size_t)((b * 8 + h) * 128) * 1024;

  for (int kt = 0; kt <= ktmax_blk; ++kt) {
    const int k0 = kt * 32;
    __syncthreads();  // previous tile fully consumed
    {
      // stage K: 32 rows x 128 shorts (16 x 16B chunks/row), 2 chunks/thread
      int ch = tid * 2;
      int r = ch >> 4, cc = (ch & 15) * 8;
      const unsigned short* gk = gkbase + (size_t)(b * kS + k0) * 3072;
      *(bf16x8*)&Ks[r * 136 + cc] = *(const bf16x8*)&gk[(size_t)r * 3072 + cc];
      int r2 = (ch + 1) >> 4, cc2 = ((ch + 1) & 15) * 8;
      *(bf16x8*)&Ks[r2 * 136 + cc2] = *(const bf16x8*)&gk[(size_t)r2 * 3072 + cc2];
      // stage V^T: 128 rows x 32 shorts (4 x 16B chunks/row), 2 chunks/thread
      int vr = ch >> 2, vc = (ch & 3) * 8;
      *(bf16x8*)&Vs[vr * 40 + vc] = *(const bf16x8*)&gvbase[(size_t)vr * 1024 + k0 + vc];
      int vr2 = (ch + 1) >> 2, vc2 = ((ch + 1) & 3) * 8;
      *(bf16x8*)&Vs[vr2 * 40 + vc2] = *(const bf16x8*)&gvbase[(size_t)vr2 * 1024 + k0 + vc2];
    }
    __syncthreads();

    if (kt <= ktmax_wav) {
      // ---- scores S[q 16][key 32] ----
      f32x4 s[2];
      s[0] = (f32x4){0.f, 0.f, 0.f, 0.f};
      s[1] = (f32x4){0.f, 0.f, 0.f, 0.f};
#pragma unroll
      for (int ns = 0; ns < 2; ns++)
#pragma unroll
        for (int ks = 0; ks < 4; ks++) {
          bf16x8 kb = *(const bf16x8*)&Ks[(ns * 16 + l15) * 136 + ks * 32 + quad * 8];
          s[ns] = __builtin_amdgcn_mfma_f32_16x16x32_bf16(qa[ks], kb, s[ns], 0, 0, 0);
        }

      // ---- causal mask (raw scores; scale folded into exp2) ----
      if (k0 + 31 > wrow0) {
#pragma unroll
        for (int r = 0; r < 4; r++) {
          int qrow = wrow0 + quad * 4 + r;
          if (k0 + l15 > qrow) s[0][r] = -1e30f;
          if (k0 + 16 + l15 > qrow) s[1][r] = -1e30f;
        }
      }

      // ---- online softmax (row = quad*4+r; cols spread over 16 lanes) ----
      float alpha[4];
#pragma unroll
      for (int r = 0; r < 4; r++) {
        float mx = fmaxf(s[0][r], s[1][r]);
        mx = fmaxf(mx, __shfl_xor(mx, 1));
        mx = fmaxf(mx, __shfl_xor(mx, 2));
        mx = fmaxf(mx, __shfl_xor(mx, 4));
        mx = fmaxf(mx, __shfl_xor(mx, 8));
        float mn = fmaxf(m_r[r], mx);
        float al = exp2f((m_r[r] - mn) * cexp);
        m_r[r] = mn;
        float p0 = exp2f((s[0][r] - mn) * cexp);
        float p1 = exp2f((s[1][r] - mn) * cexp);
        s[0][r] = p0;
        s[1][r] = p1;
        float rs = p0 + p1;
        rs += __shfl_xor(rs, 1);
        rs += __shfl_xor(rs, 2);
        rs += __shfl_xor(rs, 4);
        rs += __shfl_xor(rs, 8);
        l_r[r] = l_r[r] * al + rs;
        alpha[r] = al;
      }

      // ---- rescale O ----
#pragma unroll
      for (int dt = 0; dt < 8; dt++)
#pragma unroll
        for (int r = 0; r < 4; r++) oacc[dt][r] *= alpha[r];

      // ---- P -> LDS (per-wave), read back as A-frag ----
      unsigned short* pw = &Ps[w * 640];
#pragma unroll
      for (int r = 0; r < 4; r++) {
        int q = quad * 4 + r;
        pw[q * 40 + l15] = f2bf(s[0][r]);
        pw[q * 40 + 16 + l15] = f2bf(s[1][r]);
      }
      bf16x8 pa = *(const bf16x8*)&pw[l15 * 40 + quad * 8];

      // ---- PV: O[q][dcat] += P[q][key] * Vt[dcat][key] ----
#pragma unroll
      for (int dt = 0; dt < 8; dt++) {
        bf16x8 vb = *(const bf16x8*)&Vs[(dt * 16 + l15) * 40 + quad * 8];
        oacc[dt] = __builtin_amdgcn_mfma_f32_16x16x32_bf16(pa, vb, oacc[dt], 0, 0, 0);
      }
    }
  }

  // ---- epilogue: normalize, store [ar|ai] at merge_heads layout ----
  float inv[4];
#pragma unroll
  for (int r = 0; r < 4; r++) inv[r] = 1.f / l_r[r];
#pragma unroll
  for (int dt = 0; dt < 8; dt++) {
    int dcat = dt * 16 + l15;
    int col = (dcat < 64) ? (h * 64 + dcat) : (512 + h * 64 + dcat - 64);
#pragma unroll
    for (int r = 0; r < 4; r++) {
      int tok = b * kS + wrow0 + quad * 4 + r;
      out[(size_t)tok * 1024 + col] = f2bf(oacc[dt][r] * inv[r]);
    }
  }
}

// ---------------------------------------------------------------------------
// FFN gating in place on gu (N,8192) bf16 [gr|gi|ur|ui] -> hid in cols [0,4096)
// ---------------------------------------------------------------------------
__global__ __launch_bounds__(256) void gate_kernel(unsigned short* __restrict__ gu) {
  int id = blockIdx.x * 256 + threadIdx.x;  // 0 .. 4096*2048-1
  int n = id >> 11, m = id & 2047;
  size_t row = (size_t)n * 8192;
  float gr = bf2f(gu[row + m]);
  float gi = bf2f(gu[row + 2048 + m]);
  float ur = bf2f(gu[row + 4096 + m]);
  float ui = bf2f(gu[row + 6144 + m]);
  float mag = sqrtf(gr * gr + gi * gi);
  float s = 1.f / (1.f + __expf(-mag));
  float gar = gr * s, gai = gi * s;
  gu[row + m] = f2bf(gar * ur - gai * ui);
  gu[row + 2048 + m] = f2bf(gar * ui + gai * ur);
}

// ---------------------------------------------------------------------------
// Launcher
// ---------------------------------------------------------------------------
extern "C" void kernel_launch(void* const* d_in, const int* in_sizes, int n_in,
                              void* d_out, int out_size, void* d_ws, size_t ws_size,
                              hipStream_t stream) {
  const float* x_real = (const float*)d_in[0];
  const float* x_imag = (const float*)d_in[1];
  const float* ln1_gr = (const float*)d_in[2];
  const float* ln1_gi = (const float*)d_in[3];
  const float* ln1_br = (const float*)d_in[4];
  const float* ln1_bi = (const float*)d_in[5];
  const float* q_lm = (const float*)d_in[6];
  const float* q_ph = (const float*)d_in[7];
  const float* q_bm = (const float*)d_in[8];
  const float* q_bp = (const float*)d_in[9];
  const float* k_lm = (const float*)d_in[10];
  const float* k_ph = (const float*)d_in[11];
  const float* k_bm = (const float*)d_in[12];
  const float* k_bp = (const float*)d_in[13];
  const float* v_lm = (const float*)d_in[14];
  const float* v_ph = (const float*)d_in[15];
  const float* v_bm = (const float*)d_in[16];
  const float* v_bp = (const float*)d_in[17];
  const float* o_lm = (const float*)d_in[18];
  const float* o_ph = (const float*)d_in[19];
  const float* o_bm = (const float*)d_in[20];
  const float* o_bp = (const float*)d_in[21];
  const float* ln2_gr = (const float*)d_in[22];
  const float* ln2_gi = (const float*)d_in[23];
  const float* ln2_br = (const float*)d_in[24];
  const float* ln2_bi = (const float*)d_in[25];
  const float* gate_lm = (const float*)d_in[26];
  const float* gate_ph = (const float*)d_in[27];
  const float* up_lm = (const float*)d_in[28];
  const float* up_ph = (const float*)d_in[29];
  const float* down_lm = (const float*)d_in[30];
  const float* down_ph = (const float*)d_in[31];

  // ---- workspace layout (bytes), total 125,845,504 ----
  char* wsb = (char*)d_ws;
  unsigned short* Wqkv = (unsigned short*)(wsb + 0);           // 3072x1024 bf16
  unsigned short* Wo   = (unsigned short*)(wsb + 6291456);     // 1024x1024
  unsigned short* Wgu  = (unsigned short*)(wsb + 8388608);     // 8192x1024
  unsigned short* Wd   = (unsigned short*)(wsb + 25165824);    // 1024x4096
  float* qkvBias = (float*)(wsb + 33554432);                   // 3072 fp32
  float* oBias   = (float*)(wsb + 33566720);                   // 1024 fp32
  float* res     = (float*)(wsb + 33570816);                   // 4096x1024 fp32
  unsigned short* H = (unsigned short*)(wsb + 50348032);       // 4096x1024 bf16
  char* big = wsb + 58736640;                                  // 64 MiB region
  unsigned short* qkv     = (unsigned short*)big;              // 4096x3072 bf16
  unsigned short* attnout = (unsigned short*)(big + 25165824); // 4096x1024 bf16
  unsigned short* vtb     = (unsigned short*)(big + 33554432); // 4x8x128x1024 bf16
  unsigned short* gu      = (unsigned short*)big;              // 4096x8192 bf16 (aliases, later)

  float* outf = (float*)d_out;  // (2, 4096, 512)

  // 1) build weights + biases
  build_wcat_perm_kernel<<<1024, 256, 0, stream>>>(q_lm, q_ph, Wqkv, 0);
  build_wcat_perm_kernel<<<1024, 256, 0, stream>>>(k_lm, k_ph, Wqkv, 1);
  build_wcat_perm_kernel<<<1024, 256, 0, stream>>>(v_lm, v_ph, Wqkv, 2);
  build_wcat_kernel<<<kDD / 256, 256, 0, stream>>>(o_lm, o_ph, Wo, 512, 512, 9);
  build_wcat_kernel<<<kDH / 256, 256, 0, stream>>>(gate_lm, gate_ph, Wgu, 2048, 512, 9);
  build_wcat_kernel<<<kDH / 256, 256, 0, stream>>>(up_lm, up_ph, Wgu + (size_t)4096 * 1024, 2048, 512, 9);
  build_wcat_kernel<<<kDH / 256, 256, 0, stream>>>(down_lm, down_ph, Wd, 512, 2048, 11);
  build_bias_perm_kernel<<<2, 256, 0, stream>>>(q_bm, q_bp, qkvBias, 0);
  build_bias_perm_kernel<<<2, 256, 0, stream>>>(k_bm, k_bp, qkvBias, 1);
  build_bias_perm_kernel<<<2, 256, 0, stream>>>(v_bm, v_bp, qkvBias, 2);
  build_bias_kernel<<<2, 256, 0, stream>>>(o_bm, o_bp, oBias, 512);

  // 2) LN1: x -> H (bf16 cat)
  cln_kernel<<<kNT, 256, 0, stream>>>(x_real, x_imag, 512, ln1_gr, ln1_gi, ln1_br, ln1_bi, H);

  // 3) QKV fused GEMM (head-permuted cols; V written transposed to vtb)
  {
    dim3 g(3072 / 128, kNT / 128);
    cgemm_mfma_kernel<<<g, 256, 0, stream>>>(H, 1024, Wqkv, 1024, qkvBias, 3,
                                             nullptr, nullptr, qkv, 3072, nullptr, vtb);
  }

  // 4) RoPE in place on q,k
  rope_kernel<<<(kNT * kH * 32) / 256, 256, 0, stream>>>(qkv);

  // 5) MFMA flash attention -> attnout
  attn_mfma_kernel<<<kB * kH * (kS / 64), 256, 0, stream>>>(qkv, vtb, attnout);

  // 6) O-proj + x residual -> res fp32
  {
    dim3 g(1024 / 128, kNT / 128);
    cgemm_mfma_kernel<<<g, 256, 0, stream>>>(attnout, 1024, Wo, 1024, oBias, 1,
                                             x_real, x_imag, nullptr, 0, res, nullptr);
  }

  // 7) LN2: res -> H
  cln_kernel<<<kNT, 256, 0, stream>>>(res, res + 512, 1024, ln2_gr, ln2_gi, ln2_br, ln2_bi, H);

  // 8) gate+up fused GEMM -> gu
  {
    dim3 g(8192 / 128, kNT / 128);
    cgemm_mfma_kernel<<<g, 256, 0, stream>>>(H, 1024, Wgu, 1024, nullptr, 0,
                                             nullptr, nullptr, gu, 8192, nullptr, nullptr);
  }

  // 9) gating in place
  gate_kernel<<<(kNT * kHID) / 256, 256, 0, stream>>>(gu);

  // 10) down GEMM + residual -> d_out fp32
  {
    dim3 g(1024 / 128, kNT / 128);
    cgemm_mfma_kernel<<<g, 256, 0, stream>>>(gu, 8192, Wd, 4096, nullptr, 2,
                                             res, nullptr, nullptr, 0, outf, nullptr);
  }
}